// Round 13
// baseline (751.638 us; speedup 1.0000x reference)
//
#include <hip/hip_runtime.h>
#include <hip/hip_bf16.h>
#include <cstdint>
#include <cstddef>

typedef __bf16 bf16_t;
typedef __bf16 bf16x8 __attribute__((ext_vector_type(8)));
typedef float  f32x4  __attribute__((ext_vector_type(4)));
typedef int    int4a  __attribute__((ext_vector_type(4)));
typedef int    int4u  __attribute__((ext_vector_type(4), aligned(4)));  // 4B-aligned vec load

#define NN 50000
#define NNPAD 50176   // 392*128 = 224*224
#define NEDGE 800000
#define IND 256
#define HIDD 512
#define NLAYER 3
#define ODIM 256

#define AGG_CHUNK 224   // nodes per block (224 chunks * 224 = 50176)
#define AGG_NCH 224
#define SCAN_NB 49      // ceil(50000/1024)

// async global->LDS, 16B/lane; HW dest = wave-uniform base + lane*16
__device__ __forceinline__ void gload16(const void* g, void* l) {
  __builtin_amdgcn_global_load_lds((const __attribute__((address_space(1))) void*)g,
                                   (__attribute__((address_space(3))) void*)l, 16, 0, 0);
}

// bijective XCD swizzle (m204), bn-fastest inside each XCD chunk
__device__ __forceinline__ void xcd_bm_bn(int& bm, int& bn) {
  const int gN = gridDim.x;
  const int nwg = gN * gridDim.y;
  const int id = blockIdx.y * gN + blockIdx.x;
  const int q = nwg >> 3, r = nwg & 7;
  const int xcd = id & 7, loc = id >> 3;
  const int nid = (xcd < r ? xcd * (q + 1) : r * (q + 1) + (xcd - r) * q) + loc;
  bn = nid % gN;
  bm = nid / gN;
}

// ---------- LDS-tiled transpose + convert: Wt[n][k] = (bf16)W[k][n], z-batched ----------
__global__ __launch_bounds__(256) void k_transpose_w(const float* __restrict__ W,
                                                     bf16_t* __restrict__ Wt,
                                                     int K, int N) {
  __shared__ float t[32][33];
  size_t zo = (size_t)blockIdx.z * K * N;
  const float* Wz = W + zo;
  bf16_t* Tz = Wt + zo;
  int bx = blockIdx.x * 32;
  int by = blockIdx.y * 32;
  int tx = threadIdx.x & 31, ty = threadIdx.x >> 5;
#pragma unroll
  for (int i = 0; i < 32; i += 8) {
    int k = by + ty + i, n = bx + tx;
    t[ty + i][tx] = (k < K && n < N) ? Wz[(size_t)k * N + n] : 0.f;
  }
  __syncthreads();
#pragma unroll
  for (int i = 0; i < 32; i += 8) {
    int n = bx + ty + i, k = by + tx;
    if (n < N && k < K) Tz[(size_t)n * K + k] = (bf16_t)t[tx][ty + i];
  }
}

// ---------- CSR build ----------
__global__ void k_hist(const int* __restrict__ ei, int* __restrict__ cnt) {
  int e = blockIdx.x * 256 + threadIdx.x;
  if (e < NEDGE) atomicAdd(&cnt[ei[NEDGE + e]], 1);
}

// ---- parallel scan, phase 1: per-block local exclusive scan + block sums ----
__global__ __launch_bounds__(1024) void k_scan_local(const int* __restrict__ cnt,
                                                     int* __restrict__ off,
                                                     int* __restrict__ bsum) {
  __shared__ int s[1024];
  int b = blockIdx.x, tid = threadIdx.x;
  int idx = b * 1024 + tid;
  int v = (idx < NN) ? cnt[idx] : 0;
  s[tid] = v;
  __syncthreads();
  for (int d = 1; d < 1024; d <<= 1) {
    int t = (tid >= d) ? s[tid - d] : 0;
    __syncthreads();
    s[tid] += t;
    __syncthreads();
  }
  if (idx < NN) off[idx] = s[tid] - v;   // local exclusive
  if (tid == 1023) bsum[b] = s[1023];
}

// ---- phase 2: single wave scans block sums; writes off[NN] = total ----
__global__ __launch_bounds__(64) void k_scan_bsum(const int* __restrict__ bsum,
                                                  int* __restrict__ boff,
                                                  int* __restrict__ off) {
  int lane = threadIdx.x & 63;
  int v = (lane < SCAN_NB) ? bsum[lane] : 0;
  int inc = v;
#pragma unroll
  for (int d = 1; d < 64; d <<= 1) {
    int t = __shfl_up(inc, d, 64);
    if (lane >= d) inc += t;
  }
  if (lane < SCAN_NB) boff[lane] = inc - v;  // exclusive block offset
  if (lane == SCAN_NB - 1) off[NN] = inc;    // grand total
}

// ---- phase 3: add block offsets ----
__global__ __launch_bounds__(1024) void k_scan_add(const int* __restrict__ boff,
                                                   int* __restrict__ off) {
  int idx = blockIdx.x * 1024 + threadIdx.x;
  if (idx < NN) off[idx] += boff[blockIdx.x];
}

// scatter reuses cnt as a countdown cursor (atomicSub) -> no separate cur buffer
__global__ void k_scatter(const int* __restrict__ ei, const int* __restrict__ roff,
                          int* __restrict__ cnt, int* __restrict__ csr) {
  int e = blockIdx.x * 256 + threadIdx.x;
  if (e < NEDGE) {
    int d = ei[NEDGE + e];
    int p = atomicSub(&cnt[d], 1);
    csr[roff[d] + p - 1] = ei[e];
  }
}

// ---------- XCD-sliced aggregation, 8 nodes/wave, 4-deep gather + int4 csr batch ----------
// Slice s = blockIdx&7 (64 cols = 128B); round-robin dispatch -> per-XCD gather
// working set 6.4 MB (L2-scale). Lane-group g (8 lanes x 16B) owns node nb+g.
// Indices loaded 4-at-a-time via one dwordx4 (4B-aligned vec type) to cut VMEM
// instr/address-path cost; self-row hv hoisted above the edge loop.
__global__ __launch_bounds__(256) void k_aggregate_x(
    const bf16_t* __restrict__ h,
    const int* __restrict__ roff, const int* __restrict__ csr,
    bf16_t* __restrict__ z) {
  const int slice = blockIdx.x & 7;
  const int chunk = blockIdx.x >> 3;
  const int w = threadIdx.x >> 6;
  const int lane = threadIdx.x & 63;
  const int g = lane >> 3;        // node-group 0..7
  const int gi = lane & 7;        // lane in group -> 16B of the 128B slice
  const int colb = slice * 64 + gi * 8;
  const bf16_t* hs = h + colb;
  const int nbase = chunk * AGG_CHUNK;
#pragma unroll 1
  for (int it = 0; it < AGG_CHUNK / 32; ++it) {
    int n = nbase + it * 32 + w * 8 + g;
    bool valid = n < NN;
    int o0 = valid ? roff[n] : 0;
    int o1 = valid ? roff[n + 1] : 0;
    bf16x8 hv;
    if (valid) hv = *(const bf16x8*)(hs + (size_t)n * HIDD);
    float acc[8];
#pragma unroll
    for (int j = 0; j < 8; j++) acc[j] = 0.f;
    int e = o0;
    for (; e + 4 <= o1; e += 4) {
      int4a s4 = *(const int4u*)(csr + e);   // one dwordx4: 4 indices
      bf16x8 v0 = *(const bf16x8*)(hs + (size_t)s4.x * HIDD);
      bf16x8 v1 = *(const bf16x8*)(hs + (size_t)s4.y * HIDD);
      bf16x8 v2 = *(const bf16x8*)(hs + (size_t)s4.z * HIDD);
      bf16x8 v3 = *(const bf16x8*)(hs + (size_t)s4.w * HIDD);
#pragma unroll
      for (int j = 0; j < 8; j++)
        acc[j] += ((float)v0[j] + (float)v1[j]) + ((float)v2[j] + (float)v3[j]);
    }
    for (; e < o1; ++e) {
      int s = csr[e];
      bf16x8 v = *(const bf16x8*)(hs + (size_t)s * HIDD);
#pragma unroll
      for (int j = 0; j < 8; j++) acc[j] += (float)v[j];
    }
    if (valid) {
      bf16x8 o;
#pragma unroll
      for (int j = 0; j < 8; j++) o[j] = (bf16_t)(acc[j] + (float)hv[j]);
      *(bf16x8*)(z + (size_t)n * HIDD + colb) = o;
    }
  }
}

// ---------- in-proj GEMM (fp32 A, 128x128 tile, reg-staged A, 4 waves) ----------
__global__ __launch_bounds__(256) void k_gemm_in(
    const float* __restrict__ A, int lda, int M,
    const bf16_t* __restrict__ Bt, int K,
    const float* __restrict__ bias,
    bf16_t* __restrict__ Cb, int ldcb) {
  __shared__ char smem[32768] __attribute__((aligned(16)));
  char* ldsA = smem;
  char* ldsB = smem + 16384;

  const int tid = threadIdx.x;
  const int lane = tid & 63;
  const int w = tid >> 6;
  const int wr = w >> 1, wc = w & 1;
  const int lrow = lane & 15, lk = lane >> 4;
  int bm, bn;
  xcd_bm_bn(bm, bn);

  f32x4 acc[4][4];
#pragma unroll
  for (int m = 0; m < 4; m++)
#pragma unroll
    for (int n = 0; n < 4; n++) acc[m][n] = (f32x4){0.f, 0.f, 0.f, 0.f};

  const int srow = lane >> 3;
  const int sj = (lane & 7) ^ srow;
  const bf16_t* srcB = Bt + (size_t)(bn * 128 + srow) * K + sj * 8;

  const int ktiles = K >> 6;
  for (int kt = 0; kt < ktiles; ++kt) {
#pragma unroll
    for (int i = 0; i < 4; ++i) {
      int cb = i * 4 + w;
      gload16(srcB + (size_t)(cb * 8) * K + kt * 64, ldsB + cb * 1024);
    }
#pragma unroll
    for (int it = 0; it < 4; ++it) {
      int c = it * 256 + tid;
      int row = c >> 3, k8 = c & 7;
      int lo = (row * 128 + k8 * 16) ^ ((row & 7) << 4);
      int grow = bm * 128 + row;
      bf16x8 va;
#pragma unroll
      for (int j = 0; j < 8; j++) va[j] = (bf16_t)0.f;
      if (grow < M) {
        f32x4 u0 = *(const f32x4*)(A + (size_t)grow * lda + kt * 64 + k8 * 8);
        f32x4 u1 = *(const f32x4*)(A + (size_t)grow * lda + kt * 64 + k8 * 8 + 4);
#pragma unroll
        for (int j = 0; j < 4; j++) { va[j] = (bf16_t)u0[j]; va[4 + j] = (bf16_t)u1[j]; }
      }
      *(bf16x8*)(ldsA + lo) = va;
    }
    __syncthreads();
#pragma unroll
    for (int kk = 0; kk < 2; ++kk) {
      bf16x8 af[4], bfr[4];
#pragma unroll
      for (int m = 0; m < 4; m++) {
        int row = wr * 64 + m * 16 + lrow;
        af[m] = *(const bf16x8*)(ldsA + ((row * 128 + kk * 64 + lk * 16) ^ ((row & 7) << 4)));
      }
#pragma unroll
      for (int n = 0; n < 4; n++) {
        int col = wc * 64 + n * 16 + lrow;
        bfr[n] = *(const bf16x8*)(ldsB + ((col * 128 + kk * 64 + lk * 16) ^ ((col & 7) << 4)));
      }
#pragma unroll
      for (int m = 0; m < 4; m++)
#pragma unroll
        for (int n = 0; n < 4; n++)
          acc[m][n] = __builtin_amdgcn_mfma_f32_16x16x32_bf16(af[m], bfr[n], acc[m][n], 0, 0, 0);
    }
    __syncthreads();
  }
#pragma unroll
  for (int m = 0; m < 4; m++) {
    int rb = bm * 128 + wr * 64 + m * 16 + lk * 4;
#pragma unroll
    for (int n = 0; n < 4; n++) {
      int col = bn * 128 + wc * 64 + n * 16 + lrow;
      float bv = bias[col];
#pragma unroll
      for (int r = 0; r < 4; r++)
        Cb[(size_t)(rb + r) * ldcb + col] = (bf16_t)(acc[m][n][r] + bv);
    }
  }
}

// ---------- main bf16 GEMM: 128x128, 8 waves (512 thr), dbuf + counted vmcnt ----------
// Wave tile 32x64 (wr 0..3, wc 0..1). 4 gload16/wave/stage -> steady wait vmcnt(4).
template <int RELU>
__global__ __launch_bounds__(512) void k_gemm2(
    const bf16_t* __restrict__ A, int lda,
    const bf16_t* __restrict__ Bt, int K,
    const float* __restrict__ bias,
    bf16_t* __restrict__ Cb, int ldcb) {
  __shared__ char smem[65536] __attribute__((aligned(16)));

  const int tid = threadIdx.x;
  const int lane = tid & 63;
  const int w = tid >> 6;            // 0..7
  const int wr = w >> 1, wc = w & 1; // wr 0..3
  const int lrow = lane & 15, lk = lane >> 4;
  int bm, bn;
  xcd_bm_bn(bm, bn);

  f32x4 acc[2][4];
#pragma unroll
  for (int m = 0; m < 2; m++)
#pragma unroll
    for (int n = 0; n < 4; n++) acc[m][n] = (f32x4){0.f, 0.f, 0.f, 0.f};

  const int srow = lane >> 3;
  const int sj = (lane & 7) ^ srow;
  const bf16_t* srcA = A + (size_t)(bm * 128 + srow) * lda + sj * 8;
  const bf16_t* srcB = Bt + (size_t)(bn * 128 + srow) * K + sj * 8;

  auto STAGE = [&](int kt, int buf) {  // 4 gload16 per wave
    char* lA = smem + buf * 32768;
    char* lB = lA + 16384;
#pragma unroll
    for (int i = 0; i < 2; ++i) {
      int c = i * 8 + w;
      gload16(srcA + (size_t)(c * 8) * lda + kt * 64, lA + c * 1024);
      gload16(srcB + (size_t)(c * 8) * K + kt * 64, lB + c * 1024);
    }
  };

  STAGE(0, 0);
  STAGE(1, 1);

  const int ktiles = K >> 6;
  int cur = 0;
  for (int kt = 0; kt < ktiles; ++kt) {
    if (kt == ktiles - 1) asm volatile("s_waitcnt vmcnt(0)" ::: "memory");
    else                  asm volatile("s_waitcnt vmcnt(4)" ::: "memory");
    __builtin_amdgcn_s_barrier();
    __builtin_amdgcn_sched_barrier(0);
    char* ldsA = smem + cur * 32768;
    char* ldsB = ldsA + 16384;
#pragma unroll
    for (int kk = 0; kk < 2; ++kk) {
      bf16x8 af[2], bfr[4];
#pragma unroll
      for (int m = 0; m < 2; m++) {
        int row = wr * 32 + m * 16 + lrow;
        af[m] = *(const bf16x8*)(ldsA + ((row * 128 + kk * 64 + lk * 16) ^ ((row & 7) << 4)));
      }
#pragma unroll
      for (int n = 0; n < 4; n++) {
        int col = wc * 64 + n * 16 + lrow;
        bfr[n] = *(const bf16x8*)(ldsB + ((col * 128 + kk * 64 + lk * 16) ^ ((col & 7) << 4)));
      }
#pragma unroll
      for (int m = 0; m < 2; m++)
#pragma unroll
        for (int n = 0; n < 4; n++)
          acc[m][n] = __builtin_amdgcn_mfma_f32_16x16x32_bf16(af[m], bfr[n], acc[m][n], 0, 0, 0);
    }
    asm volatile("s_waitcnt lgkmcnt(0)" ::: "memory");
    __builtin_amdgcn_s_barrier();
    __builtin_amdgcn_sched_barrier(0);
    if (kt + 2 < ktiles) STAGE(kt + 2, cur);
    cur ^= 1;
  }

#pragma unroll
  for (int m = 0; m < 2; m++) {
    int rb = bm * 128 + wr * 32 + m * 16 + lk * 4;
#pragma unroll
    for (int n = 0; n < 4; n++) {
      int col = bn * 128 + wc * 64 + n * 16 + lrow;
      float bv = bias[col];
#pragma unroll
      for (int r = 0; r < 4; r++) {
        float v = acc[m][n][r] + bv;
        if (RELU) v = fmaxf(v, 0.f);
        Cb[(size_t)(rb + r) * ldcb + col] = (bf16_t)v;  // padded buffer
      }
    }
  }
}

// ---------- fused out-proj: 8 waves, counted-vmcnt dbuf: Cf = A1@B1t^T + A2@B2t^T ----------
template <int ACC>
__global__ __launch_bounds__(512) void k_gemm_out2(
    const bf16_t* __restrict__ A1, const bf16_t* __restrict__ A2, int lda,
    const bf16_t* __restrict__ B1t, const bf16_t* __restrict__ B2t, int K,
    const float* __restrict__ bias,
    float* __restrict__ Cf, int ldcf, int M) {
  __shared__ char smem[65536] __attribute__((aligned(16)));

  const int tid = threadIdx.x;
  const int lane = tid & 63;
  const int w = tid >> 6;
  const int wr = w >> 1, wc = w & 1;
  const int lrow = lane & 15, lk = lane >> 4;
  int bm, bn;
  xcd_bm_bn(bm, bn);

  f32x4 acc[2][4];
#pragma unroll
  for (int m = 0; m < 2; m++)
#pragma unroll
    for (int n = 0; n < 4; n++) acc[m][n] = (f32x4){0.f, 0.f, 0.f, 0.f};

  const int srow = lane >> 3;
  const int sj = (lane & 7) ^ srow;
  const size_t aoff = (size_t)(bm * 128 + srow) * lda + sj * 8;
  const size_t boff = (size_t)(bn * 128 + srow) * K + sj * 8;

  auto STAGE = [&](int kt, int buf) {  // 4 gload16 per wave
    const bf16_t* sA = (kt < 8 ? A1 : A2) + aoff + (kt & 7) * 64;
    const bf16_t* sB = (kt < 8 ? B1t : B2t) + boff + (kt & 7) * 64;
    char* lA = smem + buf * 32768;
    char* lB = lA + 16384;
#pragma unroll
    for (int i = 0; i < 2; ++i) {
      int c = i * 8 + w;
      gload16(sA + (size_t)(c * 8) * lda, lA + c * 1024);
      gload16(sB + (size_t)(c * 8) * K, lB + c * 1024);
    }
  };

  STAGE(0, 0);
  STAGE(1, 1);

  const int ktiles = 16;
  int cur = 0;
  for (int kt = 0; kt < ktiles; ++kt) {
    if (kt == ktiles - 1) asm volatile("s_waitcnt vmcnt(0)" ::: "memory");
    else                  asm volatile("s_waitcnt vmcnt(4)" ::: "memory");
    __builtin_amdgcn_s_barrier();
    __builtin_amdgcn_sched_barrier(0);
    char* ldsA = smem + cur * 32768;
    char* ldsB = ldsA + 16384;
#pragma unroll
    for (int kk = 0; kk < 2; ++kk) {
      bf16x8 af[2], bfr[4];
#pragma unroll
      for (int m = 0; m < 2; m++) {
        int row = wr * 32 + m * 16 + lrow;
        af[m] = *(const bf16x8*)(ldsA + ((row * 128 + kk * 64 + lk * 16) ^ ((row & 7) << 4)));
      }
#pragma unroll
      for (int n = 0; n < 4; n++) {
        int col = wc * 64 + n * 16 + lrow;
        bfr[n] = *(const bf16x8*)(ldsB + ((col * 128 + kk * 64 + lk * 16) ^ ((col & 7) << 4)));
      }
#pragma unroll
      for (int m = 0; m < 2; m++)
#pragma unroll
        for (int n = 0; n < 4; n++)
          acc[m][n] = __builtin_amdgcn_mfma_f32_16x16x32_bf16(af[m], bfr[n], acc[m][n], 0, 0, 0);
    }
    asm volatile("s_waitcnt lgkmcnt(0)" ::: "memory");
    __builtin_amdgcn_s_barrier();
    __builtin_amdgcn_sched_barrier(0);
    if (kt + 2 < ktiles) STAGE(kt + 2, cur);
    cur ^= 1;
  }

#pragma unroll
  for (int m = 0; m < 2; m++) {
    int rb = bm * 128 + wr * 32 + m * 16 + lk * 4;
#pragma unroll
    for (int n = 0; n < 4; n++) {
      int col = bn * 128 + wc * 64 + n * 16 + lrow;
      float bv = ACC ? 0.f : bias[col];
#pragma unroll
      for (int r = 0; r < 4; r++) {
        int row = rb + r;
        if (row < M) {
          float v = acc[m][n][r] + bv;
          if (ACC) Cf[(size_t)row * ldcf + col] += v;
          else     Cf[(size_t)row * ldcf + col] = v;
        }
      }
    }
  }
}

extern "C" void kernel_launch(void* const* d_in, const int* in_sizes, int n_in,
                              void* d_out, int out_size, void* d_ws, size_t ws_size,
                              hipStream_t stream) {
  const float* x    = (const float*)d_in[0];
  const int*   ei   = (const int*)d_in[1];
  const float* in_W = (const float*)d_in[2];
  const float* in_b = (const float*)d_in[3];
  const float* cW1  = (const float*)d_in[4];
  const float* cb1  = (const float*)d_in[5];
  const float* cW2  = (const float*)d_in[6];
  const float* cb2  = (const float*)d_in[7];
  const float* oW   = (const float*)d_in[8];
  const float* ob   = (const float*)d_in[9];
  float* out = (float*)d_out;

  char* ws = (char*)d_ws;
  size_t off = 0;
  auto alloc = [&](size_t bytes) -> char* {
    char* p = ws + off;
    off = (off + bytes + 255) & ~(size_t)255;
    return p;
  };
  bf16_t* bufA  = (bf16_t*)alloc((size_t)NNPAD * HIDD * 2);
  bf16_t* bufB  = (bf16_t*)alloc((size_t)NNPAD * HIDD * 2);
  bf16_t* bufC  = (bf16_t*)alloc((size_t)NNPAD * HIDD * 2);
  bf16_t* wt_in = (bf16_t*)alloc((size_t)IND * HIDD * 2);
  bf16_t* wt_c1 = (bf16_t*)alloc((size_t)NLAYER * HIDD * HIDD * 2);
  bf16_t* wt_c2 = (bf16_t*)alloc((size_t)NLAYER * HIDD * HIDD * 2);
  bf16_t* wt_ol = (bf16_t*)alloc((size_t)4 * ODIM * HIDD * 2);
  int* cnt  = (int*)alloc((size_t)NN * 4);
  int* roff = (int*)alloc((size_t)(NN + 1) * 4);
  int* csr  = (int*)alloc((size_t)NEDGE * 4);
  int* bsum = (int*)alloc((size_t)SCAN_NB * 4);
  int* boff = (int*)alloc((size_t)SCAN_NB * 4);

  hipMemsetAsync(cnt, 0, (size_t)NN * 4, stream);

  // ---- weight transpose/convert (z-batched) ----
  {
    dim3 g1((HIDD + 31) / 32, (IND + 31) / 32, 1);
    k_transpose_w<<<g1, 256, 0, stream>>>(in_W, wt_in, IND, HIDD);
    dim3 g2((HIDD + 31) / 32, (HIDD + 31) / 32, NLAYER);
    k_transpose_w<<<g2, 256, 0, stream>>>(cW1, wt_c1, HIDD, HIDD);
    k_transpose_w<<<g2, 256, 0, stream>>>(cW2, wt_c2, HIDD, HIDD);
    dim3 g3((ODIM + 31) / 32, (HIDD + 31) / 32, 4);
    k_transpose_w<<<g3, 256, 0, stream>>>(oW, wt_ol, HIDD, ODIM);
  }

  // ---- CSR build (parallel 3-phase scan; scatter consumes cnt) ----
  k_hist<<<(NEDGE + 255) / 256, 256, 0, stream>>>(ei, cnt);
  k_scan_local<<<SCAN_NB, 1024, 0, stream>>>(cnt, roff, bsum);
  k_scan_bsum<<<1, 64, 0, stream>>>(bsum, boff, roff);
  k_scan_add<<<SCAN_NB, 1024, 0, stream>>>(boff, roff);
  k_scatter<<<(NEDGE + 255) / 256, 256, 0, stream>>>(ei, roff, cnt, csr);

  dim3 gIn(HIDD / 128, NNPAD / 128);  // (4, 392)
  dim3 gH(HIDD / 128, NNPAD / 128);   // (4, 392)
  dim3 gO(ODIM / 128, NNPAD / 128);   // (2, 392)
  const int gAgg = 8 * AGG_NCH;       // 1792 blocks, slice = bid&7

  // ---- h0 = x @ in_W + in_b -> A ----
  k_gemm_in<<<gIn, 256, 0, stream>>>(x, IND, NN, wt_in, IND, in_b, bufA, HIDD);

  const size_t WW = (size_t)HIDD * HIDD;
  const size_t WO = (size_t)ODIM * HIDD;

  // ---- L1: agg(A)->B; C=relu(B@W1_0); B=C@W2_0 ----
  k_aggregate_x<<<gAgg, 256, 0, stream>>>(bufA, roff, csr, bufB);
  k_gemm2<1><<<gH, 512, 0, stream>>>(bufB, HIDD, wt_c1, HIDD, cb1, bufC, HIDD);
  k_gemm2<0><<<gH, 512, 0, stream>>>(bufC, HIDD, wt_c2, HIDD, cb2, bufB, HIDD);
  // ---- out = h0@O0 + h1@O1 + ob ----
  k_gemm_out2<0><<<gO, 512, 0, stream>>>(bufA, bufB, HIDD, wt_ol, wt_ol + WO, HIDD,
                                         ob, out, ODIM, NN);
  // ---- L2 ----
  k_aggregate_x<<<gAgg, 256, 0, stream>>>(bufB, roff, csr, bufA);
  k_gemm2<1><<<gH, 512, 0, stream>>>(bufA, HIDD, wt_c1 + WW, HIDD, cb1 + HIDD, bufC, HIDD);
  k_gemm2<0><<<gH, 512, 0, stream>>>(bufC, HIDD, wt_c2 + WW, HIDD, cb2 + HIDD, bufA, HIDD);
  // ---- L3 ----
  k_aggregate_x<<<gAgg, 256, 0, stream>>>(bufA, roff, csr, bufB);
  k_gemm2<1><<<gH, 512, 0, stream>>>(bufB, HIDD, wt_c1 + 2 * WW, HIDD, cb1 + 2 * HIDD, bufC, HIDD);
  k_gemm2<0><<<gH, 512, 0, stream>>>(bufC, HIDD, wt_c2 + 2 * WW, HIDD, cb2 + 2 * HIDD, bufB, HIDD);
  // ---- out += h2@O2 + h3@O3 ----
  k_gemm_out2<1><<<gO, 512, 0, stream>>>(bufA, bufB, HIDD, wt_ol + 2 * WO, wt_ol + 3 * WO, HIDD,
                                         nullptr, out, ODIM, NN);
}

// Round 14
// 738.952 us; speedup vs baseline: 1.0172x; 1.0172x over previous
//
#include <hip/hip_runtime.h>
#include <hip/hip_bf16.h>
#include <cstdint>
#include <cstddef>

typedef __bf16 bf16_t;
typedef __bf16 bf16x8 __attribute__((ext_vector_type(8)));
typedef float  f32x4  __attribute__((ext_vector_type(4)));
typedef int    int4a  __attribute__((ext_vector_type(4)));
typedef int    int4u  __attribute__((ext_vector_type(4), aligned(4)));  // 4B-aligned vec load

#define NN 50000
#define NNPAD 50176   // 392*128 = 784*64
#define NEDGE 800000
#define IND 256
#define HIDD 512
#define NLAYER 3
#define ODIM 256

#define AGG_CHUNK 64    // nodes per block (784 chunks * 64 = 50176): fine chunks for load balance
#define AGG_NCH 784
#define SCAN_NB 49      // ceil(50000/1024)

// async global->LDS, 16B/lane; HW dest = wave-uniform base + lane*16
__device__ __forceinline__ void gload16(const void* g, void* l) {
  __builtin_amdgcn_global_load_lds((const __attribute__((address_space(1))) void*)g,
                                   (__attribute__((address_space(3))) void*)l, 16, 0, 0);
}

// bijective XCD swizzle (m204), bn-fastest inside each XCD chunk
__device__ __forceinline__ void xcd_bm_bn(int& bm, int& bn) {
  const int gN = gridDim.x;
  const int nwg = gN * gridDim.y;
  const int id = blockIdx.y * gN + blockIdx.x;
  const int q = nwg >> 3, r = nwg & 7;
  const int xcd = id & 7, loc = id >> 3;
  const int nid = (xcd < r ? xcd * (q + 1) : r * (q + 1) + (xcd - r) * q) + loc;
  bn = nid % gN;
  bm = nid / gN;
}

// ---------- LDS-tiled transpose + convert: Wt[n][k] = (bf16)W[k][n], z-batched ----------
__global__ __launch_bounds__(256) void k_transpose_w(const float* __restrict__ W,
                                                     bf16_t* __restrict__ Wt,
                                                     int K, int N) {
  __shared__ float t[32][33];
  size_t zo = (size_t)blockIdx.z * K * N;
  const float* Wz = W + zo;
  bf16_t* Tz = Wt + zo;
  int bx = blockIdx.x * 32;
  int by = blockIdx.y * 32;
  int tx = threadIdx.x & 31, ty = threadIdx.x >> 5;
#pragma unroll
  for (int i = 0; i < 32; i += 8) {
    int k = by + ty + i, n = bx + tx;
    t[ty + i][tx] = (k < K && n < N) ? Wz[(size_t)k * N + n] : 0.f;
  }
  __syncthreads();
#pragma unroll
  for (int i = 0; i < 32; i += 8) {
    int n = bx + ty + i, k = by + tx;
    if (n < N && k < K) Tz[(size_t)n * K + k] = (bf16_t)t[tx][ty + i];
  }
}

// ---------- fp32 -> bf16 convert (x8 per thread) ----------
__global__ __launch_bounds__(256) void k_convert(const float* __restrict__ x,
                                                 bf16_t* __restrict__ y, int n8) {
  int i = blockIdx.x * 256 + threadIdx.x;
  if (i < n8) {
    f32x4 u0 = *(const f32x4*)(x + (size_t)i * 8);
    f32x4 u1 = *(const f32x4*)(x + (size_t)i * 8 + 4);
    bf16x8 o;
#pragma unroll
    for (int j = 0; j < 4; j++) { o[j] = (bf16_t)u0[j]; o[4 + j] = (bf16_t)u1[j]; }
    *(bf16x8*)(y + (size_t)i * 8) = o;
  }
}

// ---------- CSR build ----------
__global__ void k_hist(const int* __restrict__ ei, int* __restrict__ cnt) {
  int e = blockIdx.x * 256 + threadIdx.x;
  if (e < NEDGE) atomicAdd(&cnt[ei[NEDGE + e]], 1);
}

// ---- parallel scan, phase 1: per-block local exclusive scan + block sums ----
__global__ __launch_bounds__(1024) void k_scan_local(const int* __restrict__ cnt,
                                                     int* __restrict__ off,
                                                     int* __restrict__ bsum) {
  __shared__ int s[1024];
  int b = blockIdx.x, tid = threadIdx.x;
  int idx = b * 1024 + tid;
  int v = (idx < NN) ? cnt[idx] : 0;
  s[tid] = v;
  __syncthreads();
  for (int d = 1; d < 1024; d <<= 1) {
    int t = (tid >= d) ? s[tid - d] : 0;
    __syncthreads();
    s[tid] += t;
    __syncthreads();
  }
  if (idx < NN) off[idx] = s[tid] - v;   // local exclusive
  if (tid == 1023) bsum[b] = s[1023];
}

// ---- phase 2: single wave scans block sums; writes off[NN] = total ----
__global__ __launch_bounds__(64) void k_scan_bsum(const int* __restrict__ bsum,
                                                  int* __restrict__ boff,
                                                  int* __restrict__ off) {
  int lane = threadIdx.x & 63;
  int v = (lane < SCAN_NB) ? bsum[lane] : 0;
  int inc = v;
#pragma unroll
  for (int d = 1; d < 64; d <<= 1) {
    int t = __shfl_up(inc, d, 64);
    if (lane >= d) inc += t;
  }
  if (lane < SCAN_NB) boff[lane] = inc - v;  // exclusive block offset
  if (lane == SCAN_NB - 1) off[NN] = inc;    // grand total
}

// ---- phase 3: add block offsets ----
__global__ __launch_bounds__(1024) void k_scan_add(const int* __restrict__ boff,
                                                   int* __restrict__ off) {
  int idx = blockIdx.x * 1024 + threadIdx.x;
  if (idx < NN) off[idx] += boff[blockIdx.x];
}

// scatter reuses cnt as a countdown cursor (atomicSub) -> no separate cur buffer
__global__ void k_scatter(const int* __restrict__ ei, const int* __restrict__ roff,
                          int* __restrict__ cnt, int* __restrict__ csr) {
  int e = blockIdx.x * 256 + threadIdx.x;
  if (e < NEDGE) {
    int d = ei[NEDGE + e];
    int p = atomicSub(&cnt[d], 1);
    csr[roff[d] + p - 1] = ei[e];
  }
}

// ---------- XCD-sliced aggregation, 8 nodes/wave, 4-deep gather + int4 csr batch ----------
// Slice s = blockIdx&7 (64 cols = 128B); round-robin dispatch -> per-XCD gather
// working set 6.4 MB (L2-scale). Lane-group g (8 lanes x 16B) owns node nb+g.
// Fine chunks (64 nodes/block, 6272 blocks = 24.5/CU) smooth degree-variance tail.
__global__ __launch_bounds__(256) void k_aggregate_x(
    const bf16_t* __restrict__ h,
    const int* __restrict__ roff, const int* __restrict__ csr,
    bf16_t* __restrict__ z) {
  const int slice = blockIdx.x & 7;
  const int chunk = blockIdx.x >> 3;
  const int w = threadIdx.x >> 6;
  const int lane = threadIdx.x & 63;
  const int g = lane >> 3;        // node-group 0..7
  const int gi = lane & 7;        // lane in group -> 16B of the 128B slice
  const int colb = slice * 64 + gi * 8;
  const bf16_t* hs = h + colb;
  const int nbase = chunk * AGG_CHUNK;
#pragma unroll 1
  for (int it = 0; it < AGG_CHUNK / 32; ++it) {
    int n = nbase + it * 32 + w * 8 + g;
    bool valid = n < NN;
    int o0 = valid ? roff[n] : 0;
    int o1 = valid ? roff[n + 1] : 0;
    bf16x8 hv;
    if (valid) hv = *(const bf16x8*)(hs + (size_t)n * HIDD);
    float acc[8];
#pragma unroll
    for (int j = 0; j < 8; j++) acc[j] = 0.f;
    int e = o0;
    for (; e + 4 <= o1; e += 4) {
      int4a s4 = *(const int4u*)(csr + e);   // one dwordx4: 4 indices
      bf16x8 v0 = *(const bf16x8*)(hs + (size_t)s4.x * HIDD);
      bf16x8 v1 = *(const bf16x8*)(hs + (size_t)s4.y * HIDD);
      bf16x8 v2 = *(const bf16x8*)(hs + (size_t)s4.z * HIDD);
      bf16x8 v3 = *(const bf16x8*)(hs + (size_t)s4.w * HIDD);
#pragma unroll
      for (int j = 0; j < 8; j++)
        acc[j] += ((float)v0[j] + (float)v1[j]) + ((float)v2[j] + (float)v3[j]);
    }
    for (; e < o1; ++e) {
      int s = csr[e];
      bf16x8 v = *(const bf16x8*)(hs + (size_t)s * HIDD);
#pragma unroll
      for (int j = 0; j < 8; j++) acc[j] += (float)v[j];
    }
    if (valid) {
      bf16x8 o;
#pragma unroll
      for (int j = 0; j < 8; j++) o[j] = (bf16_t)(acc[j] + (float)hv[j]);
      *(bf16x8*)(z + (size_t)n * HIDD + colb) = o;
    }
  }
}

// ---------- main bf16 GEMM: 128x128, 8 waves (512 thr), dbuf + counted vmcnt ----------
// Wave tile 32x64 (wr 0..3, wc 0..1). 4 gload16/wave/stage -> steady wait vmcnt(4).
template <int RELU>
__global__ __launch_bounds__(512) void k_gemm2(
    const bf16_t* __restrict__ A, int lda,
    const bf16_t* __restrict__ Bt, int K,
    const float* __restrict__ bias,
    bf16_t* __restrict__ Cb, int ldcb) {
  __shared__ char smem[65536] __attribute__((aligned(16)));

  const int tid = threadIdx.x;
  const int lane = tid & 63;
  const int w = tid >> 6;            // 0..7
  const int wr = w >> 1, wc = w & 1; // wr 0..3
  const int lrow = lane & 15, lk = lane >> 4;
  int bm, bn;
  xcd_bm_bn(bm, bn);

  f32x4 acc[2][4];
#pragma unroll
  for (int m = 0; m < 2; m++)
#pragma unroll
    for (int n = 0; n < 4; n++) acc[m][n] = (f32x4){0.f, 0.f, 0.f, 0.f};

  const int srow = lane >> 3;
  const int sj = (lane & 7) ^ srow;
  const bf16_t* srcA = A + (size_t)(bm * 128 + srow) * lda + sj * 8;
  const bf16_t* srcB = Bt + (size_t)(bn * 128 + srow) * K + sj * 8;

  auto STAGE = [&](int kt, int buf) {  // 4 gload16 per wave
    char* lA = smem + buf * 32768;
    char* lB = lA + 16384;
#pragma unroll
    for (int i = 0; i < 2; ++i) {
      int c = i * 8 + w;
      gload16(srcA + (size_t)(c * 8) * lda + kt * 64, lA + c * 1024);
      gload16(srcB + (size_t)(c * 8) * K + kt * 64, lB + c * 1024);
    }
  };

  STAGE(0, 0);
  STAGE(1, 1);

  const int ktiles = K >> 6;
  int cur = 0;
  for (int kt = 0; kt < ktiles; ++kt) {
    if (kt == ktiles - 1) asm volatile("s_waitcnt vmcnt(0)" ::: "memory");
    else                  asm volatile("s_waitcnt vmcnt(4)" ::: "memory");
    __builtin_amdgcn_s_barrier();
    __builtin_amdgcn_sched_barrier(0);
    char* ldsA = smem + cur * 32768;
    char* ldsB = ldsA + 16384;
#pragma unroll
    for (int kk = 0; kk < 2; ++kk) {
      bf16x8 af[2], bfr[4];
#pragma unroll
      for (int m = 0; m < 2; m++) {
        int row = wr * 32 + m * 16 + lrow;
        af[m] = *(const bf16x8*)(ldsA + ((row * 128 + kk * 64 + lk * 16) ^ ((row & 7) << 4)));
      }
#pragma unroll
      for (int n = 0; n < 4; n++) {
        int col = wc * 64 + n * 16 + lrow;
        bfr[n] = *(const bf16x8*)(ldsB + ((col * 128 + kk * 64 + lk * 16) ^ ((col & 7) << 4)));
      }
#pragma unroll
      for (int m = 0; m < 2; m++)
#pragma unroll
        for (int n = 0; n < 4; n++)
          acc[m][n] = __builtin_amdgcn_mfma_f32_16x16x32_bf16(af[m], bfr[n], acc[m][n], 0, 0, 0);
    }
    asm volatile("s_waitcnt lgkmcnt(0)" ::: "memory");
    __builtin_amdgcn_s_barrier();
    __builtin_amdgcn_sched_barrier(0);
    if (kt + 2 < ktiles) STAGE(kt + 2, cur);
    cur ^= 1;
  }

#pragma unroll
  for (int m = 0; m < 2; m++) {
    int rb = bm * 128 + wr * 32 + m * 16 + lk * 4;
#pragma unroll
    for (int n = 0; n < 4; n++) {
      int col = bn * 128 + wc * 64 + n * 16 + lrow;
      float bv = bias[col];
#pragma unroll
      for (int r = 0; r < 4; r++) {
        float v = acc[m][n][r] + bv;
        if (RELU) v = fmaxf(v, 0.f);
        Cb[(size_t)(rb + r) * ldcb + col] = (bf16_t)v;  // padded buffer
      }
    }
  }
}

// ---------- fused out-proj: 8 waves, counted-vmcnt dbuf: Cf = A1@B1t^T + A2@B2t^T ----------
template <int ACC>
__global__ __launch_bounds__(512) void k_gemm_out2(
    const bf16_t* __restrict__ A1, const bf16_t* __restrict__ A2, int lda,
    const bf16_t* __restrict__ B1t, const bf16_t* __restrict__ B2t, int K,
    const float* __restrict__ bias,
    float* __restrict__ Cf, int ldcf, int M) {
  __shared__ char smem[65536] __attribute__((aligned(16)));

  const int tid = threadIdx.x;
  const int lane = tid & 63;
  const int w = tid >> 6;
  const int wr = w >> 1, wc = w & 1;
  const int lrow = lane & 15, lk = lane >> 4;
  int bm, bn;
  xcd_bm_bn(bm, bn);

  f32x4 acc[2][4];
#pragma unroll
  for (int m = 0; m < 2; m++)
#pragma unroll
    for (int n = 0; n < 4; n++) acc[m][n] = (f32x4){0.f, 0.f, 0.f, 0.f};

  const int srow = lane >> 3;
  const int sj = (lane & 7) ^ srow;
  const size_t aoff = (size_t)(bm * 128 + srow) * lda + sj * 8;
  const size_t boff = (size_t)(bn * 128 + srow) * K + sj * 8;

  auto STAGE = [&](int kt, int buf) {  // 4 gload16 per wave
    const bf16_t* sA = (kt < 8 ? A1 : A2) + aoff + (kt & 7) * 64;
    const bf16_t* sB = (kt < 8 ? B1t : B2t) + boff + (kt & 7) * 64;
    char* lA = smem + buf * 32768;
    char* lB = lA + 16384;
#pragma unroll
    for (int i = 0; i < 2; ++i) {
      int c = i * 8 + w;
      gload16(sA + (size_t)(c * 8) * lda, lA + c * 1024);
      gload16(sB + (size_t)(c * 8) * K, lB + c * 1024);
    }
  };

  STAGE(0, 0);
  STAGE(1, 1);

  const int ktiles = 16;
  int cur = 0;
  for (int kt = 0; kt < ktiles; ++kt) {
    if (kt == ktiles - 1) asm volatile("s_waitcnt vmcnt(0)" ::: "memory");
    else                  asm volatile("s_waitcnt vmcnt(4)" ::: "memory");
    __builtin_amdgcn_s_barrier();
    __builtin_amdgcn_sched_barrier(0);
    char* ldsA = smem + cur * 32768;
    char* ldsB = ldsA + 16384;
#pragma unroll
    for (int kk = 0; kk < 2; ++kk) {
      bf16x8 af[2], bfr[4];
#pragma unroll
      for (int m = 0; m < 2; m++) {
        int row = wr * 32 + m * 16 + lrow;
        af[m] = *(const bf16x8*)(ldsA + ((row * 128 + kk * 64 + lk * 16) ^ ((row & 7) << 4)));
      }
#pragma unroll
      for (int n = 0; n < 4; n++) {
        int col = wc * 64 + n * 16 + lrow;
        bfr[n] = *(const bf16x8*)(ldsB + ((col * 128 + kk * 64 + lk * 16) ^ ((col & 7) << 4)));
      }
#pragma unroll
      for (int m = 0; m < 2; m++)
#pragma unroll
        for (int n = 0; n < 4; n++)
          acc[m][n] = __builtin_amdgcn_mfma_f32_16x16x32_bf16(af[m], bfr[n], acc[m][n], 0, 0, 0);
    }
    asm volatile("s_waitcnt lgkmcnt(0)" ::: "memory");
    __builtin_amdgcn_s_barrier();
    __builtin_amdgcn_sched_barrier(0);
    if (kt + 2 < ktiles) STAGE(kt + 2, cur);
    cur ^= 1;
  }

#pragma unroll
  for (int m = 0; m < 2; m++) {
    int rb = bm * 128 + wr * 32 + m * 16 + lk * 4;
#pragma unroll
    for (int n = 0; n < 4; n++) {
      int col = bn * 128 + wc * 64 + n * 16 + lrow;
      float bv = ACC ? 0.f : bias[col];
#pragma unroll
      for (int r = 0; r < 4; r++) {
        int row = rb + r;
        if (row < M) {
          float v = acc[m][n][r] + bv;
          if (ACC) Cf[(size_t)row * ldcf + col] += v;
          else     Cf[(size_t)row * ldcf + col] = v;
        }
      }
    }
  }
}

extern "C" void kernel_launch(void* const* d_in, const int* in_sizes, int n_in,
                              void* d_out, int out_size, void* d_ws, size_t ws_size,
                              hipStream_t stream) {
  const float* x    = (const float*)d_in[0];
  const int*   ei   = (const int*)d_in[1];
  const float* in_W = (const float*)d_in[2];
  const float* in_b = (const float*)d_in[3];
  const float* cW1  = (const float*)d_in[4];
  const float* cb1  = (const float*)d_in[5];
  const float* cW2  = (const float*)d_in[6];
  const float* cb2  = (const float*)d_in[7];
  const float* oW   = (const float*)d_in[8];
  const float* ob   = (const float*)d_in[9];
  float* out = (float*)d_out;

  char* ws = (char*)d_ws;
  size_t off = 0;
  auto alloc = [&](size_t bytes) -> char* {
    char* p = ws + off;
    off = (off + bytes + 255) & ~(size_t)255;
    return p;
  };
  bf16_t* bufA  = (bf16_t*)alloc((size_t)NNPAD * HIDD * 2);
  bf16_t* bufB  = (bf16_t*)alloc((size_t)NNPAD * HIDD * 2);
  bf16_t* bufC  = (bf16_t*)alloc((size_t)NNPAD * HIDD * 2);
  bf16_t* wt_in = (bf16_t*)alloc((size_t)IND * HIDD * 2);
  bf16_t* wt_c1 = (bf16_t*)alloc((size_t)NLAYER * HIDD * HIDD * 2);
  bf16_t* wt_c2 = (bf16_t*)alloc((size_t)NLAYER * HIDD * HIDD * 2);
  bf16_t* wt_ol = (bf16_t*)alloc((size_t)4 * ODIM * HIDD * 2);
  int* cnt  = (int*)alloc((size_t)NN * 4);
  int* roff = (int*)alloc((size_t)(NN + 1) * 4);
  int* csr  = (int*)alloc((size_t)NEDGE * 4);
  int* bsum = (int*)alloc((size_t)SCAN_NB * 4);
  int* boff = (int*)alloc((size_t)SCAN_NB * 4);

  hipMemsetAsync(cnt, 0, (size_t)NN * 4, stream);

  // ---- weight transpose/convert (z-batched) ----
  {
    dim3 g1((HIDD + 31) / 32, (IND + 31) / 32, 1);
    k_transpose_w<<<g1, 256, 0, stream>>>(in_W, wt_in, IND, HIDD);
    dim3 g2((HIDD + 31) / 32, (HIDD + 31) / 32, NLAYER);
    k_transpose_w<<<g2, 256, 0, stream>>>(cW1, wt_c1, HIDD, HIDD);
    k_transpose_w<<<g2, 256, 0, stream>>>(cW2, wt_c2, HIDD, HIDD);
    dim3 g3((ODIM + 31) / 32, (HIDD + 31) / 32, 4);
    k_transpose_w<<<g3, 256, 0, stream>>>(oW, wt_ol, HIDD, ODIM);
  }

  // ---- CSR build (parallel 3-phase scan; scatter consumes cnt) ----
  k_hist<<<(NEDGE + 255) / 256, 256, 0, stream>>>(ei, cnt);
  k_scan_local<<<SCAN_NB, 1024, 0, stream>>>(cnt, roff, bsum);
  k_scan_bsum<<<1, 64, 0, stream>>>(bsum, boff, roff);
  k_scan_add<<<SCAN_NB, 1024, 0, stream>>>(boff, roff);
  k_scatter<<<(NEDGE + 255) / 256, 256, 0, stream>>>(ei, roff, cnt, csr);

  dim3 gH(HIDD / 128, NNPAD / 128);   // (4, 392)
  dim3 gO(ODIM / 128, NNPAD / 128);   // (2, 392)
  const int gAgg = 8 * AGG_NCH;       // 6272 blocks, slice = bid&7

  // ---- x -> bf16 (scratch in bufC, overwritten later) ----
  bf16_t* xb = bufC;
  k_convert<<<(NN * IND / 8 + 255) / 256, 256, 0, stream>>>(x, xb, NN * IND / 8);

  // ---- h0 = x @ in_W + in_b -> A (pipelined K=256 path) ----
  k_gemm2<0><<<gH, 512, 0, stream>>>(xb, IND, wt_in, IND, in_b, bufA, HIDD);

  const size_t WW = (size_t)HIDD * HIDD;
  const size_t WO = (size_t)ODIM * HIDD;

  // ---- L1: agg(A)->B; C=relu(B@W1_0); B=C@W2_0 ----
  k_aggregate_x<<<gAgg, 256, 0, stream>>>(bufA, roff, csr, bufB);
  k_gemm2<1><<<gH, 512, 0, stream>>>(bufB, HIDD, wt_c1, HIDD, cb1, bufC, HIDD);
  k_gemm2<0><<<gH, 512, 0, stream>>>(bufC, HIDD, wt_c2, HIDD, cb2, bufB, HIDD);
  // ---- out = h0@O0 + h1@O1 + ob ----
  k_gemm_out2<0><<<gO, 512, 0, stream>>>(bufA, bufB, HIDD, wt_ol, wt_ol + WO, HIDD,
                                         ob, out, ODIM, NN);
  // ---- L2 ----
  k_aggregate_x<<<gAgg, 256, 0, stream>>>(bufB, roff, csr, bufA);
  k_gemm2<1><<<gH, 512, 0, stream>>>(bufA, HIDD, wt_c1 + WW, HIDD, cb1 + HIDD, bufC, HIDD);
  k_gemm2<0><<<gH, 512, 0, stream>>>(bufC, HIDD, wt_c2 + WW, HIDD, cb2 + HIDD, bufA, HIDD);
  // ---- L3 ----
  k_aggregate_x<<<gAgg, 256, 0, stream>>>(bufA, roff, csr, bufB);
  k_gemm2<1><<<gH, 512, 0, stream>>>(bufB, HIDD, wt_c1 + 2 * WW, HIDD, cb1 + 2 * HIDD, bufC, HIDD);
  k_gemm2<0><<<gH, 512, 0, stream>>>(bufC, HIDD, wt_c2 + 2 * WW, HIDD, cb2 + 2 * HIDD, bufB, HIDD);
  // ---- out += h2@O2 + h3@O3 ----
  k_gemm_out2<1><<<gO, 512, 0, stream>>>(bufA, bufB, HIDD, wt_ol + 2 * WO, wt_ol + 3 * WO, HIDD,
                                         nullptr, out, ODIM, NN);
}

// Round 15
// 728.923 us; speedup vs baseline: 1.0312x; 1.0138x over previous
//
#include <hip/hip_runtime.h>
#include <hip/hip_bf16.h>
#include <cstdint>
#include <cstddef>

typedef __bf16 bf16_t;
typedef __bf16 bf16x8 __attribute__((ext_vector_type(8)));
typedef float  f32x4  __attribute__((ext_vector_type(4)));
typedef int    int4a  __attribute__((ext_vector_type(4)));
typedef int    int4u  __attribute__((ext_vector_type(4), aligned(4)));  // 4B-aligned vec load

#define NN 50000
#define NNPAD 50176   // 392*128 = 784*64
#define NEDGE 800000
#define IND 256
#define HIDD 512
#define NLAYER 3
#define ODIM 256

#define AGG_CHUNK 64    // nodes per block (784 chunks * 64 = 50176): fine chunks for load balance
#define AGG_NCH 784
#define SCAN_NB 49      // ceil(50000/1024)

// async global->LDS, 16B/lane; HW dest = wave-uniform base + lane*16
__device__ __forceinline__ void gload16(const void* g, void* l) {
  __builtin_amdgcn_global_load_lds((const __attribute__((address_space(1))) void*)g,
                                   (__attribute__((address_space(3))) void*)l, 16, 0, 0);
}

// bijective XCD swizzle (m204), bn-fastest inside each XCD chunk
__device__ __forceinline__ void xcd_bm_bn(int& bm, int& bn) {
  const int gN = gridDim.x;
  const int nwg = gN * gridDim.y;
  const int id = blockIdx.y * gN + blockIdx.x;
  const int q = nwg >> 3, r = nwg & 7;
  const int xcd = id & 7, loc = id >> 3;
  const int nid = (xcd < r ? xcd * (q + 1) : r * (q + 1) + (xcd - r) * q) + loc;
  bn = nid % gN;
  bm = nid / gN;
}

// ---------- LDS-tiled transpose + convert: Wt[n][k] = (bf16)W[k][n], z-batched ----------
__global__ __launch_bounds__(256) void k_transpose_w(const float* __restrict__ W,
                                                     bf16_t* __restrict__ Wt,
                                                     int K, int N) {
  __shared__ float t[32][33];
  size_t zo = (size_t)blockIdx.z * K * N;
  const float* Wz = W + zo;
  bf16_t* Tz = Wt + zo;
  int bx = blockIdx.x * 32;
  int by = blockIdx.y * 32;
  int tx = threadIdx.x & 31, ty = threadIdx.x >> 5;
#pragma unroll
  for (int i = 0; i < 32; i += 8) {
    int k = by + ty + i, n = bx + tx;
    t[ty + i][tx] = (k < K && n < N) ? Wz[(size_t)k * N + n] : 0.f;
  }
  __syncthreads();
#pragma unroll
  for (int i = 0; i < 32; i += 8) {
    int n = bx + ty + i, k = by + tx;
    if (n < N && k < K) Tz[(size_t)n * K + k] = (bf16_t)t[tx][ty + i];
  }
}

// ---------- fp32 -> bf16 convert (x8 per thread) ----------
__global__ __launch_bounds__(256) void k_convert(const float* __restrict__ x,
                                                 bf16_t* __restrict__ y, int n8) {
  int i = blockIdx.x * 256 + threadIdx.x;
  if (i < n8) {
    f32x4 u0 = *(const f32x4*)(x + (size_t)i * 8);
    f32x4 u1 = *(const f32x4*)(x + (size_t)i * 8 + 4);
    bf16x8 o;
#pragma unroll
    for (int j = 0; j < 4; j++) { o[j] = (bf16_t)u0[j]; o[4 + j] = (bf16_t)u1[j]; }
    *(bf16x8*)(y + (size_t)i * 8) = o;
  }
}

// ---------- CSR build ----------
__global__ void k_hist(const int* __restrict__ ei, int* __restrict__ cnt) {
  int e = blockIdx.x * 256 + threadIdx.x;
  if (e < NEDGE) atomicAdd(&cnt[ei[NEDGE + e]], 1);
}

// ---- parallel scan, phase 1: per-block local exclusive scan + block sums ----
__global__ __launch_bounds__(1024) void k_scan_local(const int* __restrict__ cnt,
                                                     int* __restrict__ off,
                                                     int* __restrict__ bsum) {
  __shared__ int s[1024];
  int b = blockIdx.x, tid = threadIdx.x;
  int idx = b * 1024 + tid;
  int v = (idx < NN) ? cnt[idx] : 0;
  s[tid] = v;
  __syncthreads();
  for (int d = 1; d < 1024; d <<= 1) {
    int t = (tid >= d) ? s[tid - d] : 0;
    __syncthreads();
    s[tid] += t;
    __syncthreads();
  }
  if (idx < NN) off[idx] = s[tid] - v;   // local exclusive
  if (tid == 1023) bsum[b] = s[1023];
}

// ---- phase 2: single wave scans block sums; writes off[NN] = total ----
__global__ __launch_bounds__(64) void k_scan_bsum(const int* __restrict__ bsum,
                                                  int* __restrict__ boff,
                                                  int* __restrict__ off) {
  int lane = threadIdx.x & 63;
  int v = (lane < SCAN_NB) ? bsum[lane] : 0;
  int inc = v;
#pragma unroll
  for (int d = 1; d < 64; d <<= 1) {
    int t = __shfl_up(inc, d, 64);
    if (lane >= d) inc += t;
  }
  if (lane < SCAN_NB) boff[lane] = inc - v;  // exclusive block offset
  if (lane == SCAN_NB - 1) off[NN] = inc;    // grand total
}

// ---- phase 3: add block offsets ----
__global__ __launch_bounds__(1024) void k_scan_add(const int* __restrict__ boff,
                                                   int* __restrict__ off) {
  int idx = blockIdx.x * 1024 + threadIdx.x;
  if (idx < NN) off[idx] += boff[blockIdx.x];
}

// scatter reuses cnt as a countdown cursor (atomicSub) -> no separate cur buffer
__global__ void k_scatter(const int* __restrict__ ei, const int* __restrict__ roff,
                          int* __restrict__ cnt, int* __restrict__ csr) {
  int e = blockIdx.x * 256 + threadIdx.x;
  if (e < NEDGE) {
    int d = ei[NEDGE + e];
    int p = atomicSub(&cnt[d], 1);
    csr[roff[d] + p - 1] = ei[e];
  }
}

// ---------- XCD-sliced aggregation, 8 nodes/wave, 4-deep gather + int4 csr batch ----------
// Structural floor ~90 us (5 variants tried); latency-bound at 65% occupancy.
__global__ __launch_bounds__(256) void k_aggregate_x(
    const bf16_t* __restrict__ h,
    const int* __restrict__ roff, const int* __restrict__ csr,
    bf16_t* __restrict__ z) {
  const int slice = blockIdx.x & 7;
  const int chunk = blockIdx.x >> 3;
  const int w = threadIdx.x >> 6;
  const int lane = threadIdx.x & 63;
  const int g = lane >> 3;        // node-group 0..7
  const int gi = lane & 7;        // lane in group -> 16B of the 128B slice
  const int colb = slice * 64 + gi * 8;
  const bf16_t* hs = h + colb;
  const int nbase = chunk * AGG_CHUNK;
#pragma unroll 1
  for (int it = 0; it < AGG_CHUNK / 32; ++it) {
    int n = nbase + it * 32 + w * 8 + g;
    bool valid = n < NN;
    int o0 = valid ? roff[n] : 0;
    int o1 = valid ? roff[n + 1] : 0;
    bf16x8 hv;
    if (valid) hv = *(const bf16x8*)(hs + (size_t)n * HIDD);
    float acc[8];
#pragma unroll
    for (int j = 0; j < 8; j++) acc[j] = 0.f;
    int e = o0;
    for (; e + 4 <= o1; e += 4) {
      int4a s4 = *(const int4u*)(csr + e);   // one dwordx4: 4 indices
      bf16x8 v0 = *(const bf16x8*)(hs + (size_t)s4.x * HIDD);
      bf16x8 v1 = *(const bf16x8*)(hs + (size_t)s4.y * HIDD);
      bf16x8 v2 = *(const bf16x8*)(hs + (size_t)s4.z * HIDD);
      bf16x8 v3 = *(const bf16x8*)(hs + (size_t)s4.w * HIDD);
#pragma unroll
      for (int j = 0; j < 8; j++)
        acc[j] += ((float)v0[j] + (float)v1[j]) + ((float)v2[j] + (float)v3[j]);
    }
    for (; e < o1; ++e) {
      int s = csr[e];
      bf16x8 v = *(const bf16x8*)(hs + (size_t)s * HIDD);
#pragma unroll
      for (int j = 0; j < 8; j++) acc[j] += (float)v[j];
    }
    if (valid) {
      bf16x8 o;
#pragma unroll
      for (int j = 0; j < 8; j++) o[j] = (bf16_t)(acc[j] + (float)hv[j]);
      *(bf16x8*)(z + (size_t)n * HIDD + colb) = o;
    }
  }
}

// ---------- main bf16 GEMM: 128x128, 8 waves, dbuf + counted vmcnt + early stage ----------
// Per iter: wait vmcnt(4) -> barrier -> ds_read kk0 -> MFMA kk0 -> ds_read kk1 ->
// lgkm0 -> barrier -> STAGE(kt+2) -> MFMA kk1. Stage issues 8 MFMAs earlier than
// before: in-flight window ~1.5 iters covers HBM latency on streamed A.
template <int RELU>
__global__ __launch_bounds__(512) void k_gemm2(
    const bf16_t* __restrict__ A, int lda,
    const bf16_t* __restrict__ Bt, int K,
    const float* __restrict__ bias,
    bf16_t* __restrict__ Cb, int ldcb) {
  __shared__ char smem[65536] __attribute__((aligned(16)));

  const int tid = threadIdx.x;
  const int lane = tid & 63;
  const int w = tid >> 6;            // 0..7
  const int wr = w >> 1, wc = w & 1; // wr 0..3
  const int lrow = lane & 15, lk = lane >> 4;
  int bm, bn;
  xcd_bm_bn(bm, bn);

  f32x4 acc[2][4];
#pragma unroll
  for (int m = 0; m < 2; m++)
#pragma unroll
    for (int n = 0; n < 4; n++) acc[m][n] = (f32x4){0.f, 0.f, 0.f, 0.f};

  const int srow = lane >> 3;
  const int sj = (lane & 7) ^ srow;
  const bf16_t* srcA = A + (size_t)(bm * 128 + srow) * lda + sj * 8;
  const bf16_t* srcB = Bt + (size_t)(bn * 128 + srow) * K + sj * 8;

  auto STAGE = [&](int kt, int buf) {  // 4 gload16 per wave
    char* lA = smem + buf * 32768;
    char* lB = lA + 16384;
#pragma unroll
    for (int i = 0; i < 2; ++i) {
      int c = i * 8 + w;
      gload16(srcA + (size_t)(c * 8) * lda + kt * 64, lA + c * 1024);
      gload16(srcB + (size_t)(c * 8) * K + kt * 64, lB + c * 1024);
    }
  };

  STAGE(0, 0);
  STAGE(1, 1);

  const int ktiles = K >> 6;
  int cur = 0;
  for (int kt = 0; kt < ktiles; ++kt) {
    if (kt == ktiles - 1) asm volatile("s_waitcnt vmcnt(0)" ::: "memory");
    else                  asm volatile("s_waitcnt vmcnt(4)" ::: "memory");
    __builtin_amdgcn_s_barrier();
    __builtin_amdgcn_sched_barrier(0);
    char* ldsA = smem + cur * 32768;
    char* ldsB = ldsA + 16384;
    // ---- kk = 0: read frags, compute ----
    bf16x8 af0[2], bf0[4];
#pragma unroll
    for (int m = 0; m < 2; m++) {
      int row = wr * 32 + m * 16 + lrow;
      af0[m] = *(const bf16x8*)(ldsA + ((row * 128 + lk * 16) ^ ((row & 7) << 4)));
    }
#pragma unroll
    for (int n = 0; n < 4; n++) {
      int col = wc * 64 + n * 16 + lrow;
      bf0[n] = *(const bf16x8*)(ldsB + ((col * 128 + lk * 16) ^ ((col & 7) << 4)));
    }
#pragma unroll
    for (int m = 0; m < 2; m++)
#pragma unroll
      for (int n = 0; n < 4; n++)
        acc[m][n] = __builtin_amdgcn_mfma_f32_16x16x32_bf16(af0[m], bf0[n], acc[m][n], 0, 0, 0);
    // ---- kk = 1: read frags ----
    bf16x8 af1[2], bf1[4];
#pragma unroll
    for (int m = 0; m < 2; m++) {
      int row = wr * 32 + m * 16 + lrow;
      af1[m] = *(const bf16x8*)(ldsA + ((row * 128 + 64 + lk * 16) ^ ((row & 7) << 4)));
    }
#pragma unroll
    for (int n = 0; n < 4; n++) {
      int col = wc * 64 + n * 16 + lrow;
      bf1[n] = *(const bf16x8*)(ldsB + ((col * 128 + 64 + lk * 16) ^ ((col & 7) << 4)));
    }
    // all reads of buf[cur] done -> free it for staging kt+2
    asm volatile("s_waitcnt lgkmcnt(0)" ::: "memory");
    __builtin_amdgcn_s_barrier();
    __builtin_amdgcn_sched_barrier(0);
    if (kt + 2 < ktiles) STAGE(kt + 2, cur);
    __builtin_amdgcn_sched_barrier(0);
    // ---- kk = 1 compute (covers the just-issued stage) ----
#pragma unroll
    for (int m = 0; m < 2; m++)
#pragma unroll
      for (int n = 0; n < 4; n++)
        acc[m][n] = __builtin_amdgcn_mfma_f32_16x16x32_bf16(af1[m], bf1[n], acc[m][n], 0, 0, 0);
    cur ^= 1;
  }

#pragma unroll
  for (int m = 0; m < 2; m++) {
    int rb = bm * 128 + wr * 32 + m * 16 + lk * 4;
#pragma unroll
    for (int n = 0; n < 4; n++) {
      int col = bn * 128 + wc * 64 + n * 16 + lrow;
      float bv = bias[col];
#pragma unroll
      for (int r = 0; r < 4; r++) {
        float v = acc[m][n][r] + bv;
        if (RELU) v = fmaxf(v, 0.f);
        Cb[(size_t)(rb + r) * ldcb + col] = (bf16_t)v;  // padded buffer
      }
    }
  }
}

// ---------- fused out-proj: 8 waves, counted-vmcnt dbuf + early stage ----------
template <int ACC>
__global__ __launch_bounds__(512) void k_gemm_out2(
    const bf16_t* __restrict__ A1, const bf16_t* __restrict__ A2, int lda,
    const bf16_t* __restrict__ B1t, const bf16_t* __restrict__ B2t, int K,
    const float* __restrict__ bias,
    float* __restrict__ Cf, int ldcf, int M) {
  __shared__ char smem[65536] __attribute__((aligned(16)));

  const int tid = threadIdx.x;
  const int lane = tid & 63;
  const int w = tid >> 6;
  const int wr = w >> 1, wc = w & 1;
  const int lrow = lane & 15, lk = lane >> 4;
  int bm, bn;
  xcd_bm_bn(bm, bn);

  f32x4 acc[2][4];
#pragma unroll
  for (int m = 0; m < 2; m++)
#pragma unroll
    for (int n = 0; n < 4; n++) acc[m][n] = (f32x4){0.f, 0.f, 0.f, 0.f};

  const int srow = lane >> 3;
  const int sj = (lane & 7) ^ srow;
  const size_t aoff = (size_t)(bm * 128 + srow) * lda + sj * 8;
  const size_t boff = (size_t)(bn * 128 + srow) * K + sj * 8;

  auto STAGE = [&](int kt, int buf) {  // 4 gload16 per wave
    const bf16_t* sA = (kt < 8 ? A1 : A2) + aoff + (kt & 7) * 64;
    const bf16_t* sB = (kt < 8 ? B1t : B2t) + boff + (kt & 7) * 64;
    char* lA = smem + buf * 32768;
    char* lB = lA + 16384;
#pragma unroll
    for (int i = 0; i < 2; ++i) {
      int c = i * 8 + w;
      gload16(sA + (size_t)(c * 8) * lda, lA + c * 1024);
      gload16(sB + (size_t)(c * 8) * K, lB + c * 1024);
    }
  };

  STAGE(0, 0);
  STAGE(1, 1);

  const int ktiles = 16;
  int cur = 0;
  for (int kt = 0; kt < ktiles; ++kt) {
    if (kt == ktiles - 1) asm volatile("s_waitcnt vmcnt(0)" ::: "memory");
    else                  asm volatile("s_waitcnt vmcnt(4)" ::: "memory");
    __builtin_amdgcn_s_barrier();
    __builtin_amdgcn_sched_barrier(0);
    char* ldsA = smem + cur * 32768;
    char* ldsB = ldsA + 16384;
    bf16x8 af0[2], bf0[4];
#pragma unroll
    for (int m = 0; m < 2; m++) {
      int row = wr * 32 + m * 16 + lrow;
      af0[m] = *(const bf16x8*)(ldsA + ((row * 128 + lk * 16) ^ ((row & 7) << 4)));
    }
#pragma unroll
    for (int n = 0; n < 4; n++) {
      int col = wc * 64 + n * 16 + lrow;
      bf0[n] = *(const bf16x8*)(ldsB + ((col * 128 + lk * 16) ^ ((col & 7) << 4)));
    }
#pragma unroll
    for (int m = 0; m < 2; m++)
#pragma unroll
      for (int n = 0; n < 4; n++)
        acc[m][n] = __builtin_amdgcn_mfma_f32_16x16x32_bf16(af0[m], bf0[n], acc[m][n], 0, 0, 0);
    bf16x8 af1[2], bf1[4];
#pragma unroll
    for (int m = 0; m < 2; m++) {
      int row = wr * 32 + m * 16 + lrow;
      af1[m] = *(const bf16x8*)(ldsA + ((row * 128 + 64 + lk * 16) ^ ((row & 7) << 4)));
    }
#pragma unroll
    for (int n = 0; n < 4; n++) {
      int col = wc * 64 + n * 16 + lrow;
      bf1[n] = *(const bf16x8*)(ldsB + ((col * 128 + 64 + lk * 16) ^ ((col & 7) << 4)));
    }
    asm volatile("s_waitcnt lgkmcnt(0)" ::: "memory");
    __builtin_amdgcn_s_barrier();
    __builtin_amdgcn_sched_barrier(0);
    if (kt + 2 < ktiles) STAGE(kt + 2, cur);
    __builtin_amdgcn_sched_barrier(0);
#pragma unroll
    for (int m = 0; m < 2; m++)
#pragma unroll
      for (int n = 0; n < 4; n++)
        acc[m][n] = __builtin_amdgcn_mfma_f32_16x16x32_bf16(af1[m], bf1[n], acc[m][n], 0, 0, 0);
    cur ^= 1;
  }

#pragma unroll
  for (int m = 0; m < 2; m++) {
    int rb = bm * 128 + wr * 32 + m * 16 + lk * 4;
#pragma unroll
    for (int n = 0; n < 4; n++) {
      int col = bn * 128 + wc * 64 + n * 16 + lrow;
      float bv = ACC ? 0.f : bias[col];
#pragma unroll
      for (int r = 0; r < 4; r++) {
        int row = rb + r;
        if (row < M) {
          float v = acc[m][n][r] + bv;
          if (ACC) Cf[(size_t)row * ldcf + col] += v;
          else     Cf[(size_t)row * ldcf + col] = v;
        }
      }
    }
  }
}

extern "C" void kernel_launch(void* const* d_in, const int* in_sizes, int n_in,
                              void* d_out, int out_size, void* d_ws, size_t ws_size,
                              hipStream_t stream) {
  const float* x    = (const float*)d_in[0];
  const int*   ei   = (const int*)d_in[1];
  const float* in_W = (const float*)d_in[2];
  const float* in_b = (const float*)d_in[3];
  const float* cW1  = (const float*)d_in[4];
  const float* cb1  = (const float*)d_in[5];
  const float* cW2  = (const float*)d_in[6];
  const float* cb2  = (const float*)d_in[7];
  const float* oW   = (const float*)d_in[8];
  const float* ob   = (const float*)d_in[9];
  float* out = (float*)d_out;

  char* ws = (char*)d_ws;
  size_t off = 0;
  auto alloc = [&](size_t bytes) -> char* {
    char* p = ws + off;
    off = (off + bytes + 255) & ~(size_t)255;
    return p;
  };
  bf16_t* bufA  = (bf16_t*)alloc((size_t)NNPAD * HIDD * 2);
  bf16_t* bufB  = (bf16_t*)alloc((size_t)NNPAD * HIDD * 2);
  bf16_t* bufC  = (bf16_t*)alloc((size_t)NNPAD * HIDD * 2);
  bf16_t* wt_in = (bf16_t*)alloc((size_t)IND * HIDD * 2);
  bf16_t* wt_c1 = (bf16_t*)alloc((size_t)NLAYER * HIDD * HIDD * 2);
  bf16_t* wt_c2 = (bf16_t*)alloc((size_t)NLAYER * HIDD * HIDD * 2);
  bf16_t* wt_ol = (bf16_t*)alloc((size_t)4 * ODIM * HIDD * 2);
  int* cnt  = (int*)alloc((size_t)NN * 4);
  int* roff = (int*)alloc((size_t)(NN + 1) * 4);
  int* csr  = (int*)alloc((size_t)NEDGE * 4);
  int* bsum = (int*)alloc((size_t)SCAN_NB * 4);
  int* boff = (int*)alloc((size_t)SCAN_NB * 4);

  hipMemsetAsync(cnt, 0, (size_t)NN * 4, stream);

  // ---- weight transpose/convert (z-batched) ----
  {
    dim3 g1((HIDD + 31) / 32, (IND + 31) / 32, 1);
    k_transpose_w<<<g1, 256, 0, stream>>>(in_W, wt_in, IND, HIDD);
    dim3 g2((HIDD + 31) / 32, (HIDD + 31) / 32, NLAYER);
    k_transpose_w<<<g2, 256, 0, stream>>>(cW1, wt_c1, HIDD, HIDD);
    k_transpose_w<<<g2, 256, 0, stream>>>(cW2, wt_c2, HIDD, HIDD);
    dim3 g3((ODIM + 31) / 32, (HIDD + 31) / 32, 4);
    k_transpose_w<<<g3, 256, 0, stream>>>(oW, wt_ol, HIDD, ODIM);
  }

  // ---- CSR build (parallel 3-phase scan; scatter consumes cnt) ----
  k_hist<<<(NEDGE + 255) / 256, 256, 0, stream>>>(ei, cnt);
  k_scan_local<<<SCAN_NB, 1024, 0, stream>>>(cnt, roff, bsum);
  k_scan_bsum<<<1, 64, 0, stream>>>(bsum, boff, roff);
  k_scan_add<<<SCAN_NB, 1024, 0, stream>>>(boff, roff);
  k_scatter<<<(NEDGE + 255) / 256, 256, 0, stream>>>(ei, roff, cnt, csr);

  dim3 gH(HIDD / 128, NNPAD / 128);   // (4, 392)
  dim3 gO(ODIM / 128, NNPAD / 128);   // (2, 392)
  const int gAgg = 8 * AGG_NCH;       // 6272 blocks, slice = bid&7

  // ---- x -> bf16 (scratch in bufC, overwritten later) ----
  bf16_t* xb = bufC;
  k_convert<<<(NN * IND / 8 + 255) / 256, 256, 0, stream>>>(x, xb, NN * IND / 8);

  // ---- h0 = x @ in_W + in_b -> A (pipelined K=256 path) ----
  k_gemm2<0><<<gH, 512, 0, stream>>>(xb, IND, wt_in, IND, in_b, bufA, HIDD);

  const size_t WW = (size_t)HIDD * HIDD;
  const size_t WO = (size_t)ODIM * HIDD;

  // ---- L1: agg(A)->B; C=relu(B@W1_0); B=C@W2_0 ----
  k_aggregate_x<<<gAgg, 256, 0, stream>>>(bufA, roff, csr, bufB);
  k_gemm2<1><<<gH, 512, 0, stream>>>(bufB, HIDD, wt_c1, HIDD, cb1, bufC, HIDD);
  k_gemm2<0><<<gH, 512, 0, stream>>>(bufC, HIDD, wt_c2, HIDD, cb2, bufB, HIDD);
  // ---- out = h0@O0 + h1@O1 + ob ----
  k_gemm_out2<0><<<gO, 512, 0, stream>>>(bufA, bufB, HIDD, wt_ol, wt_ol + WO, HIDD,
                                         ob, out, ODIM, NN);
  // ---- L2 ----
  k_aggregate_x<<<gAgg, 256, 0, stream>>>(bufB, roff, csr, bufA);
  k_gemm2<1><<<gH, 512, 0, stream>>>(bufA, HIDD, wt_c1 + WW, HIDD, cb1 + HIDD, bufC, HIDD);
  k_gemm2<0><<<gH, 512, 0, stream>>>(bufC, HIDD, wt_c2 + WW, HIDD, cb2 + HIDD, bufA, HIDD);
  // ---- L3 ----
  k_aggregate_x<<<gAgg, 256, 0, stream>>>(bufA, roff, csr, bufB);
  k_gemm2<1><<<gH, 512, 0, stream>>>(bufB, HIDD, wt_c1 + 2 * WW, HIDD, cb1 + 2 * HIDD, bufC, HIDD);
  k_gemm2<0><<<gH, 512, 0, stream>>>(bufC, HIDD, wt_c2 + 2 * WW, HIDD, cb2 + 2 * HIDD, bufB, HIDD);
  // ---- out += h2@O2 + h3@O3 ----
  k_gemm_out2<1><<<gO, 512, 0, stream>>>(bufA, bufB, HIDD, wt_ol + 2 * WO, wt_ol + 3 * WO, HIDD,
                                         nullptr, out, ODIM, NN);
}